// Round 1
// baseline (321.517 us; speedup 1.0000x reference)
//
#include <hip/hip_runtime.h>
#include <stdint.h>

typedef int v4i __attribute__((ext_vector_type(4)));
typedef int v16i __attribute__((ext_vector_type(16)));

// dims: B=16, C=256, H=W=56, padded 58x58, NPIX=50176

// ---------------- hyper-network ----------------

__global__ void norm2_kernel(const float* __restrict__ W2, float* __restrict__ nrm) {
  int j = blockIdx.x * 256 + threadIdx.x;   // [0,1024)
  const float* r = W2 + (size_t)j * 64;
  double s = 0.0;
  #pragma unroll 8
  for (int e = 0; e < 64; ++e) { double w = r[e]; s += w * w; }
  nrm[j] = sqrtf((float)s + 1e-6f);
}

__global__ void bias_kernel(const float* __restrict__ z, const float* __restrict__ W0,
                            int* __restrict__ bout) {
  int t = threadIdx.x;
  int o = t >> 4, j = t & 15;
  const float* zr = z + (size_t)o * 1024;
  const float* wr = W0 + (size_t)j * 1024;
  double acc = 0.0;
  for (int k = 0; k < 1024; ++k) acc += (double)zr[k] * (double)wr[k];
  bout[t] = (acc > 0.0) ? 1 : ((acc < 0.0) ? -1 : 0);
}

__global__ void hyper_kernel(const float* __restrict__ z, const float* __restrict__ W2,
                             const float* __restrict__ W3, const float* __restrict__ nrm,
                             int8_t* __restrict__ Wb) {
  __shared__ float ldsW[256 * 65];
  __shared__ float hbuf[1024];
  __shared__ float zsh[64];
  const int tid = threadIdx.x;
  const int oi = blockIdx.x;            // o*16+i
  if (tid < 64) zsh[tid] = z[(size_t)oi * 64 + tid];
  __syncthreads();
  for (int ch = 0; ch < 4; ++ch) {
    for (int idx = tid; idx < 16384; idx += 256) {
      int row = idx >> 6, e = idx & 63;
      ldsW[row * 65 + e] = W2[(size_t)(ch * 256 + row) * 64 + e];
    }
    __syncthreads();
    double acc = 0.0;
    #pragma unroll 8
    for (int e = 0; e < 64; ++e) acc += (double)zsh[e] * (double)ldsW[tid * 65 + e];
    hbuf[ch * 256 + tid] = (float)(acc / (double)nrm[ch * 256 + tid]);
    __syncthreads();
  }
  for (int idx = tid; idx < 9216; idx += 256) {
    int row = idx >> 6, e = idx & 63;
    ldsW[row * 65 + e] = W3[idx];
  }
  __syncthreads();
  const int o = oi >> 4, ii = oi & 15;
  for (int k = 0; k < 9; ++k) {
    int idx = k * 256 + tid;            // 0..2303
    int q = idx / 144, jj = idx - q * 144;
    const float* hh = &hbuf[q * 64];
    const float* wr = &ldsW[jj * 65];
    double acc = 0.0;
    #pragma unroll 8
    for (int e = 0; e < 64; ++e) acc += (double)hh[e] * (double)wr[e];
    int8_t sgn = (acc > 0.0) ? (int8_t)1 : ((acc < 0.0) ? (int8_t)(-1) : (int8_t)0);
    int tp = jj / 9, tap = jj - tp * 9;
    int co = o * 16 + q, ci = ii * 16 + tp;
    Wb[((size_t)tap * 256 + co) * 256 + ci] = sgn;
  }
}

// ---------------- sign(x) -> padded NHWC int8 ----------------

__global__ void signx_kernel(const float* __restrict__ x, int8_t* __restrict__ Sp) {
  __shared__ int8_t t[56 * 256];
  const int tid = threadIdx.x;
  const int h = blockIdx.x, b = blockIdx.y;
  const float* xb = x + (size_t)b * 802816 + (size_t)h * 56;
  for (int i = 0; i < 56; ++i) {
    int flat = i * 256 + tid;           // 14336 = 256c * 56w
    int c = flat / 56, w = flat - c * 56;
    float v = xb[(size_t)c * 3136 + w];
    t[w * 256 + (c ^ ((w & 31) << 3))] = (v > 0.f) ? 1 : ((v < 0.f) ? -1 : 0);
  }
  __syncthreads();
  int8_t* dst = Sp + (((size_t)b * 58 + h + 1) * 58 + 1) * 256;
  for (int i = 0; i < 7; ++i) {
    int f8 = i * 256 + tid;             // 1792 8-byte chunks
    int w = f8 >> 5, c0 = (f8 & 31) << 3;
    uint2 v = *(const uint2*)&t[w * 256 + (c0 ^ ((w & 31) << 3))];
    *(uint2*)(dst + (size_t)w * 256 + c0) = v;
  }
}

// ---------------- binarized 3x3 conv via i8 MFMA implicit GEMM ----------------
// grid (14,16), block 512. Tile: 224 px (4 rows) x 256 co. raw = conv + bias (i16, NHWC)

__global__ __launch_bounds__(512) void conv_kernel(
    const int8_t* __restrict__ Sp, const int8_t* __restrict__ Wb,
    const int* __restrict__ bias, int16_t* __restrict__ raw)
{
  __shared__ __align__(16) int8_t lds[89088 + 2 * 16384];
  int8_t* Wl = lds + 89088;
  const int tid = threadIdx.x;
  const int lane = tid & 63;
  const int b = blockIdx.y;
  const int h0 = blockIdx.x << 2;

  // stage input tile: 6 rows x 58 cols x 256 ch; 16B-granule XOR swizzle keyed by col&7
  {
    const int8_t* SpB = Sp + ((size_t)b * 58 + h0) * 58 * 256;
    #pragma unroll
    for (int it = 0; it < 11; ++it) {
      int G = it * 512 + tid;
      if (G < 5568) {
        int pp = G >> 4, gl = G & 15;
        int wp = pp % 58;
        v4i v = *(const v4i*)(SpB + pp * 256 + ((gl ^ (wp & 7)) << 4));
        *(v4i*)(lds + (G << 4)) = v;
      }
    }
  }

  const int co_w = tid & 255, kg_w = (tid >> 8) & 1;
  // W chunk ks=(tap*4+c64); LDS layout per buffer: [c2][kg][co256][16B]
#define WSRC(ks, c2) ((const v4i*)(Wb + (((size_t)((ks) >> 2) * 256 + co_w) << 8) \
                      + (((ks) & 3) << 6) + ((c2) << 5) + (kg_w << 4)))
  v4i PA0 = *WSRC(0, 0), PA1 = *WSRC(0, 1);
  v4i PB0 = *WSRC(1, 0), PB1 = *WSRC(1, 1);
  *(v4i*)(Wl + tid * 16) = PA0;
  *(v4i*)(Wl + (tid + 512) * 16) = PA1;
  PA0 = *WSRC(2, 0); PA1 = *WSRC(2, 1);
  __syncthreads();

  const int n = lane & 31, kg = lane >> 5;
  const int wid = tid >> 6;
  const int pxgrp = wid >> 2, cogrp = wid & 3;
  const int nf = pxgrp ? 3 : 4;   // px fragments: grp0 -> 0..3, grp1 -> 4..6
  int pixoff[4], wcol[4];
  #pragma unroll
  for (int f = 0; f < 4; ++f) {
    int px = ((pxgrp << 2) + f) * 32 + n;
    if (px > 223) px = 223;       // unused slot (grp1 f=3), clamped
    int hh = px / 56, ww = px - hh * 56;
    pixoff[f] = hh * 58 + ww;
    wcol[f] = ww;
  }
  const int aoff0 = (kg * 256 + cogrp * 64 + n) << 4;
  const int aoff1 = aoff0 + (32 << 4);

  v16i acc[4][2];
  #pragma unroll
  for (int f = 0; f < 4; ++f)
    #pragma unroll
    for (int a = 0; a < 2; ++a)
      #pragma unroll
      for (int e = 0; e < 16; ++e) acc[f][a][e] = 0;

  int ks = 0;
  for (int r = 0; r < 3; ++r) {
    for (int s = 0; s < 3; ++s) {
      int pb[4], ky[4];
      #pragma unroll
      for (int f = 0; f < 4; ++f) {
        pb[f] = (pixoff[f] + r * 58 + s) << 8;
        ky[f] = (wcol[f] + s) & 7;
      }
      #pragma unroll
      for (int c64 = 0; c64 < 4; ++c64) {
        const int cur = ks & 1;
        const int8_t* Wc = Wl + cur * 16384;
        #pragma unroll
        for (int c2 = 0; c2 < 2; ++c2) {
          const int gb = (c64 << 2) + (c2 << 1) + kg;  // source granule (0..15)
          v4i Af0 = *(const v4i*)(Wc + (c2 << 13) + aoff0);
          v4i Af1 = *(const v4i*)(Wc + (c2 << 13) + aoff1);
          #pragma unroll
          for (int f = 0; f < 4; ++f) {
            if (f < nf) {
              v4i Bf = *(const v4i*)(lds + pb[f] + ((gb ^ ky[f]) << 4));
              acc[f][0] = __builtin_amdgcn_mfma_i32_32x32x32_i8(Af0, Bf, acc[f][0], 0, 0, 0);
              acc[f][1] = __builtin_amdgcn_mfma_i32_32x32x32_i8(Af1, Bf, acc[f][1], 0, 0, 0);
            }
          }
        }
        // double-buffered W pipeline (depth-2 register prefetch)
        if (ks + 1 < 36) {
          int8_t* Wn = Wl + ((cur ^ 1) * 16384);
          if ((ks & 1) == 0) { *(v4i*)(Wn + tid * 16) = PB0; *(v4i*)(Wn + (tid + 512) * 16) = PB1; }
          else               { *(v4i*)(Wn + tid * 16) = PA0; *(v4i*)(Wn + (tid + 512) * 16) = PA1; }
        }
        if (ks + 3 < 36) {
          if ((ks & 1) == 0) { PB0 = *WSRC(ks + 3, 0); PB1 = *WSRC(ks + 3, 1); }
          else               { PA0 = *WSRC(ks + 3, 0); PA1 = *WSRC(ks + 3, 1); }
        }
        ++ks;
        __syncthreads();
      }
    }
  }
#undef WSRC

  // epilogue: v = acc + bias -> i16 NHWC
  const int pbase = b * 3136 + h0 * 56;
  #pragma unroll
  for (int f = 0; f < 4; ++f) {
    if (f < nf) {
      int px = pbase + ((pxgrp << 2) + f) * 32 + n;
      int16_t* rp = raw + (size_t)px * 256;
      #pragma unroll
      for (int a = 0; a < 2; ++a) {
        #pragma unroll
        for (int q = 0; q < 4; ++q) {
          int co = cogrp * 64 + a * 32 + q * 8 + kg * 4;  // D row = (reg&3)+8*(reg>>2)+4*(lane>>5)
          v4i bi = *(const v4i*)(bias + co);
          short4 o;
          o.x = (short)(acc[f][a][q * 4 + 0] + bi.x);
          o.y = (short)(acc[f][a][q * 4 + 1] + bi.y);
          o.z = (short)(acc[f][a][q * 4 + 2] + bi.z);
          o.w = (short)(acc[f][a][q * 4 + 3] + bi.w);
          *(short4*)(rp + co) = o;
        }
      }
    }
  }
}

// ---------------- per-channel stats (exact integer sums) ----------------

__global__ void stats_kernel(const int16_t* __restrict__ raw, unsigned long long* __restrict__ sums) {
  __shared__ int ssum[256], ssq[256];
  const int tid = threadIdx.x;
  ssum[tid] = 0; ssq[tid] = 0;
  __syncthreads();
  const int c0 = (tid & 31) << 3;
  const int pxo = tid >> 5;
  const int pbase = blockIdx.x << 8;
  int s[8], q[8];
  #pragma unroll
  for (int j = 0; j < 8; ++j) { s[j] = 0; q[j] = 0; }
  for (int i = 0; i < 32; ++i) {
    int px = pbase + (i << 3) + pxo;
    v4i vv = *(const v4i*)(raw + (size_t)px * 256 + c0);
    #pragma unroll
    for (int j = 0; j < 8; ++j) {
      int wdd = vv[j >> 1];
      int v = (j & 1) ? (wdd >> 16) : (int)(short)wdd;
      s[j] += v; q[j] += v * v;
    }
  }
  #pragma unroll
  for (int j = 0; j < 8; ++j) {
    atomicAdd(&ssum[c0 + j], s[j]);
    atomicAdd(&ssq[c0 + j], q[j]);
  }
  __syncthreads();
  atomicAdd(&sums[tid], (unsigned long long)(long long)ssum[tid]);
  atomicAdd(&sums[256 + tid], (unsigned long long)(long long)ssq[tid]);
}

__global__ void finalize_kernel(const unsigned long long* __restrict__ sums,
                                const float* __restrict__ gamma, const float* __restrict__ beta,
                                float* __restrict__ par) {
  const int c = threadIdx.x;
  double S = (double)(long long)sums[c];
  double Q = (double)(long long)sums[256 + c];
  double mean = S / 50176.0;
  double var = Q / 50176.0 - mean * mean;
  double istd = 1.0 / sqrt(var + 1e-5);
  par[c] = (float)mean;
  par[256 + c] = gamma[c] * (float)istd;
  par[512 + c] = beta[c];
}

// ---------------- binarize BN1 output -> padded NHWC int8 ----------------

__global__ void binz_kernel(const int16_t* __restrict__ raw, const float* __restrict__ par,
                            int8_t* __restrict__ Sp2) {
  const int id0 = blockIdx.x * 256 + threadIdx.x;
  for (int it = 0; it < 4; ++it) {
    int id = id0 + it * 401408;
    int px = id >> 5, c0 = (id & 31) << 3;
    float m[8], A[8], bb[8];
    *(float4*)&m[0]  = *(const float4*)&par[c0];
    *(float4*)&m[4]  = *(const float4*)&par[c0 + 4];
    *(float4*)&A[0]  = *(const float4*)&par[256 + c0];
    *(float4*)&A[4]  = *(const float4*)&par[256 + c0 + 4];
    *(float4*)&bb[0] = *(const float4*)&par[512 + c0];
    *(float4*)&bb[4] = *(const float4*)&par[512 + c0 + 4];
    v4i vv = *(const v4i*)(raw + (size_t)px * 256 + c0);
    unsigned lo = 0, hi = 0;
    #pragma unroll
    for (int j = 0; j < 8; ++j) {
      int wdd = vv[j >> 1];
      int v = (j & 1) ? (wdd >> 16) : (int)(short)wdd;
      float tval = ((float)v - m[j]) * A[j] + bb[j];
      unsigned sb = (tval > 0.f) ? 1u : ((tval < 0.f) ? 0xffu : 0u);
      if (j < 4) lo |= sb << (8 * j); else hi |= sb << (8 * (j - 4));
    }
    int bq = px / 3136; int rr = px - bq * 3136;
    int hh = rr / 56, ww = rr - hh * 56;
    int8_t* dst = Sp2 + (((size_t)bq * 58 + hh + 1) * 58 + ww + 1) * 256 + c0;
    uint2 o; o.x = lo; o.y = hi;
    *(uint2*)dst = o;
  }
}

// ---------------- final: BN2 + residual, NHWC -> NCHW ----------------

__global__ void final_kernel(const int16_t* __restrict__ raw2, const float* __restrict__ par,
                             const float* __restrict__ x, float* __restrict__ out) {
  __shared__ float t[256 * 57];
  const int tid = threadIdx.x;
  const int h = blockIdx.x, b = blockIdx.y;
  const int rowp = b * 3136 + h * 56;
  for (int i = 0; i < 7; ++i) {
    int f8 = i * 256 + tid;
    int px = f8 >> 5, c0 = (f8 & 31) << 3;
    float m[8], A[8], bb[8];
    *(float4*)&m[0]  = *(const float4*)&par[c0];
    *(float4*)&m[4]  = *(const float4*)&par[c0 + 4];
    *(float4*)&A[0]  = *(const float4*)&par[256 + c0];
    *(float4*)&A[4]  = *(const float4*)&par[256 + c0 + 4];
    *(float4*)&bb[0] = *(const float4*)&par[512 + c0];
    *(float4*)&bb[4] = *(const float4*)&par[512 + c0 + 4];
    v4i vv = *(const v4i*)(raw2 + (size_t)(rowp + px) * 256 + c0);
    #pragma unroll
    for (int j = 0; j < 8; ++j) {
      int wdd = vv[j >> 1];
      int v = (j & 1) ? (wdd >> 16) : (int)(short)wdd;
      t[(c0 + j) * 57 + px] = ((float)v - m[j]) * A[j] + bb[j];
    }
  }
  __syncthreads();
  const float* xb = x + (size_t)b * 802816 + (size_t)h * 56;
  float* ob = out + (size_t)b * 802816 + (size_t)h * 56;
  const int lane = tid & 63, wv = tid >> 6;
  for (int i = 0; i < 64; ++i) {
    int c = (i << 2) + wv;
    if (lane < 56) {
      ob[(size_t)c * 3136 + lane] = t[c * 57 + lane] + xb[(size_t)c * 3136 + lane];
    }
  }
}

// ---------------- host launcher ----------------

extern "C" void kernel_launch(void* const* d_in, const int* in_sizes, int n_in,
                              void* d_out, int out_size, void* d_ws, size_t ws_size,
                              hipStream_t stream) {
  const float* x      = (const float*)d_in[0];
  const float* z1     = (const float*)d_in[1];
  const float* W0_1   = (const float*)d_in[2];
  const float* W2_1   = (const float*)d_in[3];
  const float* W3_1   = (const float*)d_in[4];
  const float* gamma1 = (const float*)d_in[5];
  const float* beta1  = (const float*)d_in[6];
  const float* z2     = (const float*)d_in[7];
  const float* W0_2   = (const float*)d_in[8];
  const float* W2_2   = (const float*)d_in[9];
  const float* W3_2   = (const float*)d_in[10];
  const float* gamma2 = (const float*)d_in[11];
  const float* beta2  = (const float*)d_in[12];
  float* out = (float*)d_out;

  char* ws = (char*)d_ws;
  size_t off = 0;
  auto alloc = [&](size_t sz) -> void* {
    void* p = ws + off;
    off += (sz + 255) & ~(size_t)255;
    return p;
  };
  int8_t* Sp1  = (int8_t*)alloc(13778944);          // 16*58*58*256
  int8_t* Sp2  = (int8_t*)alloc(13778944);
  int16_t* raw1 = (int16_t*)alloc(25690112);        // 50176*256*2
  int16_t* raw2 = (int16_t*)alloc(25690112);
  int8_t* Wb1  = (int8_t*)alloc(589824);
  int8_t* Wb2  = (int8_t*)alloc(589824);
  int* b1      = (int*)alloc(1024);
  int* b2      = (int*)alloc(1024);
  float* n2_1  = (float*)alloc(4096);
  float* n2_2  = (float*)alloc(4096);
  unsigned long long* sums = (unsigned long long*)alloc(8192); // sums1 | sums2
  float* par1  = (float*)alloc(3072);
  float* par2  = (float*)alloc(3072);
  if (ws_size < off) return;

  hipMemsetAsync(Sp1, 0, 2 * 13778944ull, stream);  // Sp1 + Sp2 (borders stay zero)
  hipMemsetAsync(sums, 0, 8192, stream);

  norm2_kernel<<<4, 256, 0, stream>>>(W2_1, n2_1);
  norm2_kernel<<<4, 256, 0, stream>>>(W2_2, n2_2);
  hyper_kernel<<<256, 256, 0, stream>>>(z1, W2_1, W3_1, n2_1, Wb1);
  hyper_kernel<<<256, 256, 0, stream>>>(z2, W2_2, W3_2, n2_2, Wb2);
  bias_kernel<<<1, 256, 0, stream>>>(z1, W0_1, b1);
  bias_kernel<<<1, 256, 0, stream>>>(z2, W0_2, b2);
  signx_kernel<<<dim3(56, 16), 256, 0, stream>>>(x, Sp1);
  conv_kernel<<<dim3(14, 16), 512, 0, stream>>>(Sp1, Wb1, b1, raw1);
  stats_kernel<<<196, 256, 0, stream>>>(raw1, sums);
  finalize_kernel<<<1, 256, 0, stream>>>(sums, gamma1, beta1, par1);
  binz_kernel<<<1568, 256, 0, stream>>>(raw1, par1, Sp2);
  conv_kernel<<<dim3(14, 16), 512, 0, stream>>>(Sp2, Wb2, b2, raw2);
  stats_kernel<<<196, 256, 0, stream>>>(raw2, sums + 512);
  finalize_kernel<<<1, 256, 0, stream>>>(sums + 512, gamma2, beta2, par2);
  final_kernel<<<dim3(56, 16), 256, 0, stream>>>(raw2, par2, x, out);
}

// Round 2
// 225.197 us; speedup vs baseline: 1.4277x; 1.4277x over previous
//
#include <hip/hip_runtime.h>
#include <stdint.h>

typedef int v4i __attribute__((ext_vector_type(4)));
typedef int v16i __attribute__((ext_vector_type(16)));

// dims: B=16, C=256, H=W=56, padded 58x58, NPIX=50176

// ---------------- hyper-network ----------------

__global__ void norm2_kernel(const float* __restrict__ W2a, const float* __restrict__ W2b,
                             float* __restrict__ nrm, unsigned long long* __restrict__ sums) {
  if (blockIdx.x == 0) {
    #pragma unroll
    for (int i = 0; i < 4; ++i) sums[i * 256 + threadIdx.x] = 0ull;
  }
  int j = blockIdx.x * 256 + threadIdx.x;   // [0,2048)
  const float* r = (j < 1024) ? (W2a + (size_t)j * 64) : (W2b + (size_t)(j - 1024) * 64);
  double s = 0.0;
  #pragma unroll 8
  for (int e = 0; e < 64; ++e) { double w = r[e]; s += w * w; }
  nrm[j] = sqrtf((float)s + 1e-6f);
}

// grid 32: bid<16 -> set1 output o=bid ; else set2 o=bid-16
__global__ void bias_kernel(const float* __restrict__ z1, const float* __restrict__ W01,
                            const float* __restrict__ z2, const float* __restrict__ W02,
                            int* __restrict__ b1, int* __restrict__ b2) {
  __shared__ float zs[1024];
  const int tid = threadIdx.x;
  const int set = blockIdx.x >> 4, o = blockIdx.x & 15;
  const float* z = set ? z2 : z1;
  const float* W0 = set ? W02 : W01;
  int* bout = set ? b2 : b1;
  #pragma unroll
  for (int i = 0; i < 4; ++i) zs[i * 256 + tid] = z[(size_t)o * 1024 + i * 256 + tid];
  __syncthreads();
  const int j = tid >> 4, l = tid & 15;
  const float* wr = W0 + (size_t)j * 1024;
  double acc = 0.0;
  #pragma unroll 4
  for (int it = 0; it < 16; ++it) {
    float4 w4 = *(const float4*)&wr[it * 64 + l * 4];
    float4 z4 = *(const float4*)&zs[it * 64 + l * 4];
    acc += (double)w4.x * z4.x + (double)w4.y * z4.y + (double)w4.z * z4.z + (double)w4.w * z4.w;
  }
  #pragma unroll
  for (int m = 1; m < 16; m <<= 1) acc += __shfl_xor(acc, m, 64);
  if (l == 0) bout[o * 16 + j] = (acc > 0.0) ? 1 : ((acc < 0.0) ? -1 : 0);
}

// grid 512: bid<256 -> set1, else set2
__global__ void hyper_kernel(const float* __restrict__ z1, const float* __restrict__ W21,
                             const float* __restrict__ W31, const float* __restrict__ z2,
                             const float* __restrict__ W22, const float* __restrict__ W32,
                             const float* __restrict__ nrm,
                             int8_t* __restrict__ Wb1, int8_t* __restrict__ Wb2) {
  __shared__ float ldsW[256 * 65];
  __shared__ float hbuf[1024];
  __shared__ float zsh[64];
  const int tid = threadIdx.x;
  const int set = blockIdx.x >> 8;
  const int oi = blockIdx.x & 255;      // o*16+i
  const float* z = set ? z2 : z1;
  const float* W2 = set ? W22 : W21;
  const float* W3 = set ? W32 : W31;
  const float* nr = nrm + set * 1024;
  int8_t* Wb = set ? Wb2 : Wb1;
  if (tid < 64) zsh[tid] = z[(size_t)oi * 64 + tid];
  __syncthreads();
  for (int ch = 0; ch < 4; ++ch) {
    for (int idx = tid; idx < 16384; idx += 256) {
      int row = idx >> 6, e = idx & 63;
      ldsW[row * 65 + e] = W2[(size_t)(ch * 256 + row) * 64 + e];
    }
    __syncthreads();
    double acc = 0.0;
    #pragma unroll 8
    for (int e = 0; e < 64; ++e) acc += (double)zsh[e] * (double)ldsW[tid * 65 + e];
    hbuf[ch * 256 + tid] = (float)(acc / (double)nr[ch * 256 + tid]);
    __syncthreads();
  }
  for (int idx = tid; idx < 9216; idx += 256) {
    int row = idx >> 6, e = idx & 63;
    ldsW[row * 65 + e] = W3[idx];
  }
  __syncthreads();
  const int o = oi >> 4, ii = oi & 15;
  for (int k = 0; k < 9; ++k) {
    int idx = k * 256 + tid;            // 0..2303
    int q = idx / 144, jj = idx - q * 144;
    const float* hh = &hbuf[q * 64];
    const float* wr = &ldsW[jj * 65];
    double acc = 0.0;
    #pragma unroll 8
    for (int e = 0; e < 64; ++e) acc += (double)hh[e] * (double)wr[e];
    int8_t sgn = (acc > 0.0) ? (int8_t)1 : ((acc < 0.0) ? (int8_t)(-1) : (int8_t)0);
    int tp = jj / 9, tap = jj - tp * 9;
    int co = o * 16 + q, ci = ii * 16 + tp;
    Wb[((size_t)tap * 256 + co) * 256 + ci] = sgn;
  }
}

// ---------------- sign(x) -> padded NHWC int8 (incl. border zeroing) ----------------

__global__ void signx_kernel(const float* __restrict__ x, int8_t* __restrict__ Sp) {
  const int tid = threadIdx.x;
  const int h = blockIdx.x, b = blockIdx.y;   // h in [0,58)
  int8_t* rowp = Sp + ((size_t)b * 58 + h) * 58 * 256;
  if (h == 0 || h == 57) {
    #pragma unroll
    for (int i = 0; i < 4; ++i) {
      int idx = i * 256 + tid;
      if (idx < 928) *(v4i*)(rowp + (size_t)idx * 16) = (v4i){0, 0, 0, 0};
    }
    return;
  }
  __shared__ int8_t t[56 * 256];
  const float* xb = x + (size_t)b * 802816 + (size_t)(h - 1) * 56;
  for (int i = 0; i < 56; ++i) {
    int flat = i * 256 + tid;           // 14336 = 256c * 56w
    int c = flat / 56, w = flat - c * 56;
    float v = xb[(size_t)c * 3136 + w];
    t[w * 256 + (c ^ ((w & 31) << 3))] = (v > 0.f) ? 1 : ((v < 0.f) ? -1 : 0);
  }
  if (tid < 32) {   // zero cols 0 and 57
    int col = tid >> 4;
    *(v4i*)(rowp + (col ? 57 * 256 : 0) + (tid & 15) * 16) = (v4i){0, 0, 0, 0};
  }
  __syncthreads();
  int8_t* dst = rowp + 256;
  for (int i = 0; i < 7; ++i) {
    int f8 = i * 256 + tid;             // 1792 8-byte chunks
    int w = f8 >> 5, c0 = (f8 & 31) << 3;
    uint2 v = *(const uint2*)&t[w * 256 + (c0 ^ ((w & 31) << 3))];
    *(uint2*)(dst + (size_t)w * 256 + c0) = v;
  }
}

// ---------------- binarized 3x3 conv via i8 MFMA implicit GEMM ----------------
// grid (14,16), block 512. A (weights) global->reg prefetch; B tile in LDS; NO K-loop barriers.

__global__ __launch_bounds__(512, 2) void conv_kernel(
    const int8_t* __restrict__ Sp, const int8_t* __restrict__ Wb,
    const int* __restrict__ bias, int16_t* __restrict__ raw)
{
  __shared__ __align__(16) int8_t lds[89088];
  const int tid = threadIdx.x;
  const int lane = tid & 63;
  const int b = blockIdx.y;
  const int h0 = blockIdx.x << 2;

  // stage input tile: 6 rows x 58 cols x 256 ch; 16B-granule XOR swizzle keyed by col&7
  {
    const int8_t* SpB = Sp + ((size_t)b * 58 + h0) * 58 * 256;
    #pragma unroll
    for (int it = 0; it < 11; ++it) {
      int G = it * 512 + tid;
      if (G < 5568) {
        int pp = G >> 4, gl = G & 15;
        int wp = pp % 58;
        v4i v = *(const v4i*)(SpB + pp * 256 + ((gl ^ (wp & 7)) << 4));
        *(v4i*)(lds + (G << 4)) = v;
      }
    }
  }

  const int n = lane & 31, kg = lane >> 5;
  const int wid = tid >> 6;
  const int pxgrp = wid >> 2, cogrp = wid & 3;
  const int nf = pxgrp ? 3 : 4;   // px fragments: grp0 -> 0..3, grp1 -> 4..6
  int pixoff[4], wcol[4];
  #pragma unroll
  for (int f = 0; f < 4; ++f) {
    int px = ((pxgrp << 2) + f) * 32 + n;
    if (px > 223) px = 223;       // unused slot (grp1 f=3), clamped
    int hh = px / 56, ww = px - hh * 56;
    pixoff[f] = hh * 58 + ww;
    wcol[f] = ww;
  }

  // A fragment base: lane (n,kg) for co-group: co = cogrp*64 + a*32 + n, ci-halves by kg
  const int8_t* Abase = Wb + (size_t)((cogrp << 6) + n) * 256 + (kg << 4);
  // full offset: + tap*65536 + c64*64 + c2*32 + a*8192

  v4i Ar[2][2][2];
  #pragma unroll
  for (int c2 = 0; c2 < 2; ++c2)
    #pragma unroll
    for (int a = 0; a < 2; ++a)
      Ar[0][c2][a] = *(const v4i*)(Abase + c2 * 32 + a * 8192);

  __syncthreads();

  v16i acc[4][2];
  #pragma unroll
  for (int f = 0; f < 4; ++f)
    #pragma unroll
    for (int a = 0; a < 2; ++a)
      #pragma unroll
      for (int e = 0; e < 16; ++e) acc[f][a][e] = 0;

  #pragma unroll
  for (int ks = 0; ks < 36; ++ks) {
    const int cur = ks & 1;
    if (ks + 1 < 36) {                     // depth-1 register prefetch of next A chunk
      const int t2 = (ks + 1) >> 2, c642 = (ks + 1) & 3;
      const int8_t* p = Abase + t2 * 65536 + c642 * 64;
      #pragma unroll
      for (int c2 = 0; c2 < 2; ++c2)
        #pragma unroll
        for (int a = 0; a < 2; ++a)
          Ar[cur ^ 1][c2][a] = *(const v4i*)(p + c2 * 32 + a * 8192);
    }
    const int tap = ks >> 2, c64 = ks & 3;
    const int r = tap / 3, s = tap - 3 * (tap / 3);
    #pragma unroll
    for (int c2 = 0; c2 < 2; ++c2) {
      v4i Af0 = Ar[cur][c2][0], Af1 = Ar[cur][c2][1];
      #pragma unroll
      for (int f = 0; f < 4; ++f) {
        if (f < nf) {
          const int gb = (c64 << 2) + (c2 << 1) + kg;
          v4i Bf = *(const v4i*)(lds + ((pixoff[f] + r * 58 + s) << 8)
                                 + ((gb ^ ((wcol[f] + s) & 7)) << 4));
          acc[f][0] = __builtin_amdgcn_mfma_i32_32x32x32_i8(Af0, Bf, acc[f][0], 0, 0, 0);
          acc[f][1] = __builtin_amdgcn_mfma_i32_32x32x32_i8(Af1, Bf, acc[f][1], 0, 0, 0);
        }
      }
    }
  }

  // epilogue: v = acc + bias -> i16 NHWC
  const int pbase = b * 3136 + h0 * 56;
  #pragma unroll
  for (int f = 0; f < 4; ++f) {
    if (f < nf) {
      int px = pbase + ((pxgrp << 2) + f) * 32 + n;
      int16_t* rp = raw + (size_t)px * 256;
      #pragma unroll
      for (int a = 0; a < 2; ++a) {
        #pragma unroll
        for (int q = 0; q < 4; ++q) {
          int co = cogrp * 64 + a * 32 + q * 8 + kg * 4;  // D row = (reg&3)+8*(reg>>2)+4*(lane>>5)
          v4i bi = *(const v4i*)(bias + co);
          short4 o;
          o.x = (short)(acc[f][a][q * 4 + 0] + bi.x);
          o.y = (short)(acc[f][a][q * 4 + 1] + bi.y);
          o.z = (short)(acc[f][a][q * 4 + 2] + bi.z);
          o.w = (short)(acc[f][a][q * 4 + 3] + bi.w);
          *(short4*)(rp + co) = o;
        }
      }
    }
  }
}

// ---------------- per-channel stats (exact integer sums) ----------------

__global__ void stats_kernel(const int16_t* __restrict__ raw, unsigned long long* __restrict__ sums) {
  __shared__ int ssum[256], ssq[256];
  const int tid = threadIdx.x;
  ssum[tid] = 0; ssq[tid] = 0;
  __syncthreads();
  const int c0 = (tid & 31) << 3;
  const int pxo = tid >> 5;
  const int pbase = blockIdx.x << 7;      // 128 px per block, 392 blocks
  int s[8], q[8];
  #pragma unroll
  for (int j = 0; j < 8; ++j) { s[j] = 0; q[j] = 0; }
  for (int i = 0; i < 16; ++i) {
    int px = pbase + (i << 3) + pxo;
    v4i vv = *(const v4i*)(raw + (size_t)px * 256 + c0);
    #pragma unroll
    for (int j = 0; j < 8; ++j) {
      int wdd = vv[j >> 1];
      int v = (j & 1) ? (wdd >> 16) : (int)(short)wdd;
      s[j] += v; q[j] += v * v;
    }
  }
  #pragma unroll
  for (int j = 0; j < 8; ++j) {
    atomicAdd(&ssum[c0 + j], s[j]);
    atomicAdd(&ssq[c0 + j], q[j]);
  }
  __syncthreads();
  atomicAdd(&sums[tid], (unsigned long long)(long long)ssum[tid]);
  atomicAdd(&sums[256 + tid], (unsigned long long)(long long)ssq[tid]);
}

__global__ void finalize_kernel(const unsigned long long* __restrict__ sums,
                                const float* __restrict__ gamma, const float* __restrict__ beta,
                                float* __restrict__ par) {
  const int c = threadIdx.x;
  double S = (double)(long long)sums[c];
  double Q = (double)(long long)sums[256 + c];
  double mean = S / 50176.0;
  double var = Q / 50176.0 - mean * mean;
  double istd = 1.0 / sqrt(var + 1e-5);
  par[c] = (float)mean;
  par[256 + c] = gamma[c] * (float)istd;
  par[512 + c] = beta[c];
}

// ---------------- binarize BN1 output -> padded NHWC int8 (incl. border zeroing) ----------------

__global__ void binz_kernel(const int16_t* __restrict__ raw, const float* __restrict__ par,
                            int8_t* __restrict__ Sp2) {
  const int tid = threadIdx.x;
  if (blockIdx.x >= 1568) {               // zero Sp2 borders (16 blocks, 1 per image)
    int img = blockIdx.x - 1568;
    int8_t* base = Sp2 + (size_t)img * 58 * 58 * 256;
    #pragma unroll
    for (int i = 0; i < 15; ++i) {
      int idx = i * 256 + tid;            // 228 border px * 16 granules = 3648
      if (idx < 3648) {
        int p = idx >> 4, g = idx & 15;
        int row, col;
        if (p < 58) { row = 0; col = p; }
        else if (p < 116) { row = 57; col = p - 58; }
        else { int k = p - 116; row = 1 + (k >> 1); col = (k & 1) ? 57 : 0; }
        *(v4i*)(base + ((size_t)(row * 58 + col)) * 256 + g * 16) = (v4i){0, 0, 0, 0};
      }
    }
    return;
  }
  const int id0 = blockIdx.x * 256 + tid;
  for (int it = 0; it < 4; ++it) {
    int id = id0 + it * 401408;
    int px = id >> 5, c0 = (id & 31) << 3;
    float m[8], A[8], bb[8];
    *(float4*)&m[0]  = *(const float4*)&par[c0];
    *(float4*)&m[4]  = *(const float4*)&par[c0 + 4];
    *(float4*)&A[0]  = *(const float4*)&par[256 + c0];
    *(float4*)&A[4]  = *(const float4*)&par[256 + c0 + 4];
    *(float4*)&bb[0] = *(const float4*)&par[512 + c0];
    *(float4*)&bb[4] = *(const float4*)&par[512 + c0 + 4];
    v4i vv = *(const v4i*)(raw + (size_t)px * 256 + c0);
    unsigned lo = 0, hi = 0;
    #pragma unroll
    for (int j = 0; j < 8; ++j) {
      int wdd = vv[j >> 1];
      int v = (j & 1) ? (wdd >> 16) : (int)(short)wdd;
      float tval = ((float)v - m[j]) * A[j] + bb[j];
      unsigned sb = (tval > 0.f) ? 1u : ((tval < 0.f) ? 0xffu : 0u);
      if (j < 4) lo |= sb << (8 * j); else hi |= sb << (8 * (j - 4));
    }
    int bq = px / 3136; int rr = px - bq * 3136;
    int hh = rr / 56, ww = rr - hh * 56;
    int8_t* dst = Sp2 + (((size_t)bq * 58 + hh + 1) * 58 + ww + 1) * 256 + c0;
    uint2 o; o.x = lo; o.y = hi;
    *(uint2*)dst = o;
  }
}

// ---------------- final: BN2 + residual, NHWC -> NCHW ----------------

__global__ void final_kernel(const int16_t* __restrict__ raw2, const float* __restrict__ par,
                             const float* __restrict__ x, float* __restrict__ out) {
  __shared__ float t[256 * 57];
  const int tid = threadIdx.x;
  const int h = blockIdx.x, b = blockIdx.y;
  const int rowp = b * 3136 + h * 56;
  for (int i = 0; i < 7; ++i) {
    int f8 = i * 256 + tid;
    int px = f8 >> 5, c0 = (f8 & 31) << 3;
    float m[8], A[8], bb[8];
    *(float4*)&m[0]  = *(const float4*)&par[c0];
    *(float4*)&m[4]  = *(const float4*)&par[c0 + 4];
    *(float4*)&A[0]  = *(const float4*)&par[256 + c0];
    *(float4*)&A[4]  = *(const float4*)&par[256 + c0 + 4];
    *(float4*)&bb[0] = *(const float4*)&par[512 + c0];
    *(float4*)&bb[4] = *(const float4*)&par[512 + c0 + 4];
    v4i vv = *(const v4i*)(raw2 + (size_t)(rowp + px) * 256 + c0);
    #pragma unroll
    for (int j = 0; j < 8; ++j) {
      int wdd = vv[j >> 1];
      int v = (j & 1) ? (wdd >> 16) : (int)(short)wdd;
      t[(c0 + j) * 57 + px] = ((float)v - m[j]) * A[j] + bb[j];
    }
  }
  __syncthreads();
  const float* xb = x + (size_t)b * 802816 + (size_t)h * 56;
  float* ob = out + (size_t)b * 802816 + (size_t)h * 56;
  for (int i = 0; i < 16; ++i) {
    int idx = i * 256 + tid;            // 256c x 16 slots (14 valid)
    int c = idx >> 4, wq = idx & 15;
    if (wq < 14) {
      int w0 = wq * 4;
      float4 xv = *(const float4*)(xb + (size_t)c * 3136 + w0);
      float4 o;
      o.x = t[c * 57 + w0 + 0] + xv.x;
      o.y = t[c * 57 + w0 + 1] + xv.y;
      o.z = t[c * 57 + w0 + 2] + xv.z;
      o.w = t[c * 57 + w0 + 3] + xv.w;
      *(float4*)(ob + (size_t)c * 3136 + w0) = o;
    }
  }
}

// ---------------- host launcher ----------------

extern "C" void kernel_launch(void* const* d_in, const int* in_sizes, int n_in,
                              void* d_out, int out_size, void* d_ws, size_t ws_size,
                              hipStream_t stream) {
  const float* x      = (const float*)d_in[0];
  const float* z1     = (const float*)d_in[1];
  const float* W0_1   = (const float*)d_in[2];
  const float* W2_1   = (const float*)d_in[3];
  const float* W3_1   = (const float*)d_in[4];
  const float* gamma1 = (const float*)d_in[5];
  const float* beta1  = (const float*)d_in[6];
  const float* z2     = (const float*)d_in[7];
  const float* W0_2   = (const float*)d_in[8];
  const float* W2_2   = (const float*)d_in[9];
  const float* W3_2   = (const float*)d_in[10];
  const float* gamma2 = (const float*)d_in[11];
  const float* beta2  = (const float*)d_in[12];
  float* out = (float*)d_out;

  char* ws = (char*)d_ws;
  size_t off = 0;
  auto alloc = [&](size_t sz) -> void* {
    void* p = ws + off;
    off += (sz + 255) & ~(size_t)255;
    return p;
  };
  int8_t* Sp1  = (int8_t*)alloc(13778944);          // 16*58*58*256
  int8_t* Sp2  = (int8_t*)alloc(13778944);
  int16_t* raw1 = (int16_t*)alloc(25690112);        // 50176*256*2
  int16_t* raw2 = (int16_t*)alloc(25690112);
  int8_t* Wb1  = (int8_t*)alloc(589824);
  int8_t* Wb2  = (int8_t*)alloc(589824);
  int* b1      = (int*)alloc(1024);
  int* b2      = (int*)alloc(1024);
  float* nrm   = (float*)alloc(8192);               // nrm1 | nrm2
  unsigned long long* sums = (unsigned long long*)alloc(8192); // sums1 | sums2
  float* par1  = (float*)alloc(3072);
  float* par2  = (float*)alloc(3072);
  if (ws_size < off) return;

  norm2_kernel<<<8, 256, 0, stream>>>(W2_1, W2_2, nrm, sums);
  hyper_kernel<<<512, 256, 0, stream>>>(z1, W2_1, W3_1, z2, W2_2, W3_2, nrm, Wb1, Wb2);
  bias_kernel<<<32, 256, 0, stream>>>(z1, W0_1, z2, W0_2, b1, b2);
  signx_kernel<<<dim3(58, 16), 256, 0, stream>>>(x, Sp1);
  conv_kernel<<<dim3(14, 16), 512, 0, stream>>>(Sp1, Wb1, b1, raw1);
  stats_kernel<<<392, 256, 0, stream>>>(raw1, sums);
  finalize_kernel<<<1, 256, 0, stream>>>(sums, gamma1, beta1, par1);
  binz_kernel<<<1584, 256, 0, stream>>>(raw1, par1, Sp2);
  conv_kernel<<<dim3(14, 16), 512, 0, stream>>>(Sp2, Wb2, b2, raw2);
  stats_kernel<<<392, 256, 0, stream>>>(raw2, sums + 512);
  finalize_kernel<<<1, 256, 0, stream>>>(sums + 512, gamma2, beta2, par2);
  final_kernel<<<dim3(56, 16), 256, 0, stream>>>(raw2, par2, x, out);
}

// Round 3
// 204.100 us; speedup vs baseline: 1.5753x; 1.1034x over previous
//
#include <hip/hip_runtime.h>
#include <stdint.h>

typedef int v4i __attribute__((ext_vector_type(4)));
typedef int v16i __attribute__((ext_vector_type(16)));

// dims: B=16, C=256, H=W=56, padded 58x58, NPIX=50176

// ---------------- prep: norm2 + bias + zero sums ----------------
// grid 40: bid 0-7 norm2 (2048 rows), bid 8-39 bias (32 outputs of 16)

__global__ void prep_kernel(const float* __restrict__ W2a, const float* __restrict__ W2b,
                            float* __restrict__ nrm, unsigned long long* __restrict__ sums,
                            const float* __restrict__ z1, const float* __restrict__ W01,
                            const float* __restrict__ z2, const float* __restrict__ W02,
                            int* __restrict__ b1, int* __restrict__ b2) {
  const int tid = threadIdx.x;
  if (blockIdx.x < 8) {
    if (blockIdx.x == 0) {
      #pragma unroll
      for (int i = 0; i < 4; ++i) sums[i * 256 + tid] = 0ull;
    }
    int j = blockIdx.x * 256 + tid;   // [0,2048)
    const float* r = (j < 1024) ? (W2a + (size_t)j * 64) : (W2b + (size_t)(j - 1024) * 64);
    double s = 0.0;
    #pragma unroll 8
    for (int e = 0; e < 64; ++e) { double w = r[e]; s += w * w; }
    nrm[j] = sqrtf((float)s + 1e-6f);
    return;
  }
  __shared__ float zs[1024];
  const int sb = blockIdx.x - 8;
  const int set = sb >> 4, o = sb & 15;
  const float* z = set ? z2 : z1;
  const float* W0 = set ? W02 : W01;
  int* bout = set ? b2 : b1;
  #pragma unroll
  for (int i = 0; i < 4; ++i) zs[i * 256 + tid] = z[(size_t)o * 1024 + i * 256 + tid];
  __syncthreads();
  const int j = tid >> 4, l = tid & 15;
  const float* wr = W0 + (size_t)j * 1024;
  double acc = 0.0;
  #pragma unroll 4
  for (int it = 0; it < 16; ++it) {
    float4 w4 = *(const float4*)&wr[it * 64 + l * 4];
    float4 z4 = *(const float4*)&zs[it * 64 + l * 4];
    acc += (double)w4.x * z4.x + (double)w4.y * z4.y + (double)w4.z * z4.z + (double)w4.w * z4.w;
  }
  #pragma unroll
  for (int m = 1; m < 16; m <<= 1) acc += __shfl_xor(acc, m, 64);
  if (l == 0) bout[o * 16 + j] = (acc > 0.0) ? 1 : ((acc < 0.0) ? -1 : 0);
}

// ---------------- hyper-network -> repacked binary weights ----------------
// WbP layout: chunk = (tap*4 + c64)*2 + c2 ; addr = chunk*8192 + co*32 + (ci&31)

__global__ void hyper_kernel(const float* __restrict__ z1, const float* __restrict__ W21,
                             const float* __restrict__ W31, const float* __restrict__ z2,
                             const float* __restrict__ W22, const float* __restrict__ W32,
                             const float* __restrict__ nrm,
                             int8_t* __restrict__ Wb1, int8_t* __restrict__ Wb2) {
  __shared__ float ldsW[256 * 65];
  __shared__ float hbuf[1024];
  __shared__ float zsh[64];
  const int tid = threadIdx.x;
  const int set = blockIdx.x >> 8;
  const int oi = blockIdx.x & 255;      // o*16+i
  const float* z = set ? z2 : z1;
  const float* W2 = set ? W22 : W21;
  const float* W3 = set ? W32 : W31;
  const float* nr = nrm + set * 1024;
  int8_t* Wb = set ? Wb2 : Wb1;
  if (tid < 64) zsh[tid] = z[(size_t)oi * 64 + tid];
  __syncthreads();
  for (int ch = 0; ch < 4; ++ch) {
    for (int idx = tid; idx < 16384; idx += 256) {
      int row = idx >> 6, e = idx & 63;
      ldsW[row * 65 + e] = W2[(size_t)(ch * 256 + row) * 64 + e];
    }
    __syncthreads();
    double acc = 0.0;
    #pragma unroll 8
    for (int e = 0; e < 64; ++e) acc += (double)zsh[e] * (double)ldsW[tid * 65 + e];
    hbuf[ch * 256 + tid] = (float)(acc / (double)nr[ch * 256 + tid]);
    __syncthreads();
  }
  for (int idx = tid; idx < 9216; idx += 256) {
    int row = idx >> 6, e = idx & 63;
    ldsW[row * 65 + e] = W3[idx];
  }
  __syncthreads();
  const int o = oi >> 4, ii = oi & 15;
  for (int k = 0; k < 9; ++k) {
    int idx = k * 256 + tid;            // 0..2303
    int q = idx / 144, jj = idx - q * 144;
    const float* hh = &hbuf[q * 64];
    const float* wr = &ldsW[jj * 65];
    double acc = 0.0;
    #pragma unroll 8
    for (int e = 0; e < 64; ++e) acc += (double)hh[e] * (double)wr[e];
    int8_t sgn = (acc > 0.0) ? (int8_t)1 : ((acc < 0.0) ? (int8_t)(-1) : (int8_t)0);
    int tp = jj / 9, tap = jj - tp * 9;
    int co = o * 16 + q, ci = ii * 16 + tp;
    int c64 = ci >> 6, c2 = (ci >> 5) & 1, cilo = ci & 31;
    Wb[(size_t)(((tap << 2) + c64) * 2 + c2) * 8192 + co * 32 + cilo] = sgn;
  }
}

// ---------------- sign(x) -> padded NHWC int8 (incl. border zeroing) ----------------

__global__ void signx_kernel(const float* __restrict__ x, int8_t* __restrict__ Sp) {
  const int tid = threadIdx.x;
  const int h = blockIdx.x, b = blockIdx.y;   // h in [0,58)
  int8_t* rowp = Sp + ((size_t)b * 58 + h) * 58 * 256;
  if (h == 0 || h == 57) {
    #pragma unroll
    for (int i = 0; i < 4; ++i) {
      int idx = i * 256 + tid;
      if (idx < 928) *(v4i*)(rowp + (size_t)idx * 16) = (v4i){0, 0, 0, 0};
    }
    return;
  }
  __shared__ int8_t t[56 * 256];
  const float* xb = x + (size_t)b * 802816 + (size_t)(h - 1) * 56;
  for (int i = 0; i < 56; ++i) {
    int flat = i * 256 + tid;           // 14336 = 256c * 56w
    int c = flat / 56, w = flat - c * 56;
    float v = xb[(size_t)c * 3136 + w];
    t[w * 256 + (c ^ ((w & 31) << 3))] = (v > 0.f) ? 1 : ((v < 0.f) ? -1 : 0);
  }
  if (tid < 32) {   // zero cols 0 and 57
    int col = tid >> 4;
    *(v4i*)(rowp + (col ? 57 * 256 : 0) + (tid & 15) * 16) = (v4i){0, 0, 0, 0};
  }
  __syncthreads();
  int8_t* dst = rowp + 256;
  for (int i = 0; i < 7; ++i) {
    int f8 = i * 256 + tid;             // 1792 8-byte chunks
    int w = f8 >> 5, c0 = (f8 & 31) << 3;
    uint2 v = *(const uint2*)&t[w * 256 + (c0 ^ ((w & 31) << 3))];
    *(uint2*)(dst + (size_t)w * 256 + c0) = v;
  }
}

// ---------------- binarized 3x3 conv via i8 MFMA implicit GEMM ----------------
// grid (14,16), block 512. Tile 224 px x 256 co.
// MODE 0: stage B from Sp (padded i8). MODE 1: stage from raw i16 + threshold-binarize.
// A (weights, repacked) global->reg, depth-2 prefetch, coalesced 2048B wave-loads.
// Epilogue: store i16 raw AND accumulate per-channel sum/sumsq (exact ints).

template <int MODE>
__global__ __launch_bounds__(512, 2) void conv_kernel(
    const int8_t* __restrict__ Sp, const int16_t* __restrict__ rawin,
    const float* __restrict__ par, const int8_t* __restrict__ WbP,
    const int* __restrict__ bias, int16_t* __restrict__ raw,
    unsigned long long* __restrict__ sums)
{
  __shared__ __align__(16) int8_t lds[89088];
  const int tid = threadIdx.x;
  const int lane = tid & 63;
  const int b = blockIdx.y;
  const int h0 = blockIdx.x << 2;

  const int n = lane & 31, kg = lane >> 5;
  const int wid = tid >> 6;
  const int pxgrp = wid >> 2, cogrp = wid & 3;
  const int nf = pxgrp ? 3 : 4;

  // ---- A prologue: chunks 0,1 into regs (issue before staging to overlap) ----
  // lane offset within chunk: (cogrp*64 + a*32 + n)*32 + kg*16
  const int8_t* Abase = WbP + (size_t)((cogrp << 6) + n) * 32 + (kg << 4);
  v4i Ar[3][2][2];   // [buf][c2][a]
  #pragma unroll
  for (int c2 = 0; c2 < 2; ++c2)
    #pragma unroll
    for (int a = 0; a < 2; ++a) {
      Ar[0][c2][a] = *(const v4i*)(Abase + (size_t)(0 * 2 + c2) * 8192 + a * 1024);
      Ar[1][c2][a] = *(const v4i*)(Abase + (size_t)(1 * 2 + c2) * 8192 + a * 1024);
    }

  // ---- stage input tile: 348 pp-granule-rows x 16 granules ----
  if (MODE == 0) {
    const int8_t* SpB = Sp + ((size_t)b * 58 + h0) * 58 * 256;
    #pragma unroll
    for (int it = 0; it < 11; ++it) {
      int G = it * 512 + tid;
      if (G < 5568) {
        int pp = G >> 4, gl = G & 15;
        int wp = pp % 58;
        v4i v = *(const v4i*)(SpB + pp * 256 + ((gl ^ (wp & 7)) << 4));
        *(v4i*)(lds + (G << 4)) = v;
      }
    }
  } else {
    // threshold-binarize from raw i16: thread owns fixed ci-granule gsrc
    const int gsrc = tid & 15;
    const int ppt = tid >> 4;
    float thr[16]; int sf[16];
    const float* thrp = par + 768;
    const int* sfp = (const int*)(par + 1024);
    #pragma unroll
    for (int j = 0; j < 16; ++j) { thr[j] = thrp[gsrc * 16 + j]; sf[j] = sfp[gsrc * 16 + j]; }
    #pragma unroll
    for (int it = 0; it < 11; ++it) {
      int pp = it * 32 + ppt;
      if (pp < 348) {
        int prow = pp / 58, pcol = pp - prow * 58;
        int ir = h0 + prow - 1, ic = pcol - 1;
        v4i outv = (v4i){0, 0, 0, 0};
        if (ir >= 0 && ir <= 55 && ic >= 0 && ic <= 55) {
          const int16_t* src = rawin + ((size_t)(b * 3136 + ir * 56 + ic)) * 256 + gsrc * 16;
          v4i lo = *(const v4i*)src;
          v4i hi = *(const v4i*)(src + 8);
          #pragma unroll
          for (int j = 0; j < 16; ++j) {
            int wd = (j < 8) ? lo[(j >> 1) & 3] : hi[(j >> 1) & 3];
            int v = (j & 1) ? (wd >> 16) : (int)(short)wd;
            float fv = (float)v;
            int bj = (fv > thr[j]) ? sf[j] : ((fv < thr[j]) ? -sf[j] : 0);
            outv[j >> 2] |= (bj & 0xff) << ((j & 3) << 3);
          }
        }
        *(v4i*)(lds + ((pp << 4) + (gsrc ^ (pcol & 7))) * 16) = outv;
      }
    }
  }

  int pixoff[4], wcol[4];
  #pragma unroll
  for (int f = 0; f < 4; ++f) {
    int px = ((pxgrp << 2) + f) * 32 + n;
    if (px > 223) px = 223;       // unused slot (grp1 f=3), clamped
    int hh = px / 56, ww = px - hh * 56;
    pixoff[f] = hh * 58 + ww;
    wcol[f] = ww;
  }

  v16i acc[4][2];
  #pragma unroll
  for (int f = 0; f < 4; ++f)
    #pragma unroll
    for (int a = 0; a < 2; ++a)
      #pragma unroll
      for (int e = 0; e < 16; ++e) acc[f][a][e] = 0;

  __syncthreads();

  #pragma unroll
  for (int ks = 0; ks < 36; ++ks) {
    if (ks + 2 < 36) {                    // depth-2 prefetch
      const int bn = (ks + 2) % 3;
      #pragma unroll
      for (int c2 = 0; c2 < 2; ++c2)
        #pragma unroll
        for (int a = 0; a < 2; ++a)
          Ar[bn][c2][a] = *(const v4i*)(Abase + (size_t)((ks + 2) * 2 + c2) * 8192 + a * 1024);
    }
    const int cur = ks % 3;
    const int tap = ks >> 2, c64 = ks & 3;
    const int r = tap / 3, s = tap - 3 * (tap / 3);
    #pragma unroll
    for (int c2 = 0; c2 < 2; ++c2) {
      v4i Af0 = Ar[cur][c2][0], Af1 = Ar[cur][c2][1];
      #pragma unroll
      for (int f = 0; f < 4; ++f) {
        if (f < nf) {
          const int gb = (c64 << 2) + (c2 << 1) + kg;
          v4i Bf = *(const v4i*)(lds + ((pixoff[f] + r * 58 + s) << 8)
                                 + ((gb ^ ((wcol[f] + s) & 7)) << 4));
          acc[f][0] = __builtin_amdgcn_mfma_i32_32x32x32_i8(Af0, Bf, acc[f][0], 0, 0, 0);
          acc[f][1] = __builtin_amdgcn_mfma_i32_32x32x32_i8(Af1, Bf, acc[f][1], 0, 0, 0);
        }
      }
    }
  }

  // ---- epilogue: store raw = acc + bias (i16 NHWC) + per-channel stats ----
  __syncthreads();                 // LDS B-tile no longer needed
  int* sred = (int*)lds;           // [0:256) sum, [256:512) sumsq
  sred[tid] = 0;
  __syncthreads();

  const int pbase = b * 3136 + h0 * 56;
  #pragma unroll
  for (int a = 0; a < 2; ++a) {
    int psum[16], psq[16];
    #pragma unroll
    for (int e = 0; e < 16; ++e) { psum[e] = 0; psq[e] = 0; }
    #pragma unroll
    for (int f = 0; f < 4; ++f) {
      if (f < nf) {
        int px = pbase + ((pxgrp << 2) + f) * 32 + n;
        int16_t* rp = raw + (size_t)px * 256;
        #pragma unroll
        for (int q = 0; q < 4; ++q) {
          int co = cogrp * 64 + a * 32 + q * 8 + kg * 4;
          v4i bi = *(const v4i*)(bias + co);
          int v0 = acc[f][a][q * 4 + 0] + bi.x;
          int v1 = acc[f][a][q * 4 + 1] + bi.y;
          int v2 = acc[f][a][q * 4 + 2] + bi.z;
          int v3 = acc[f][a][q * 4 + 3] + bi.w;
          short4 o;
          o.x = (short)v0; o.y = (short)v1; o.z = (short)v2; o.w = (short)v3;
          *(short4*)(rp + co) = o;
          psum[q * 4 + 0] += v0; psq[q * 4 + 0] += v0 * v0;
          psum[q * 4 + 1] += v1; psq[q * 4 + 1] += v1 * v1;
          psum[q * 4 + 2] += v2; psq[q * 4 + 2] += v2 * v2;
          psum[q * 4 + 3] += v3; psq[q * 4 + 3] += v3 * v3;
        }
      }
    }
    #pragma unroll
    for (int e = 0; e < 16; ++e) {
      int s1 = psum[e], s2 = psq[e];
      #pragma unroll
      for (int m = 1; m < 32; m <<= 1) {
        s1 += __shfl_xor(s1, m, 64);
        s2 += __shfl_xor(s2, m, 64);
      }
      if (n == 0) {
        int co = cogrp * 64 + a * 32 + (e >> 2) * 8 + kg * 4 + (e & 3);
        atomicAdd(&sred[co], s1);
        atomicAdd(&sred[256 + co], s2);
      }
    }
  }
  __syncthreads();
  if (tid < 256) {
    atomicAdd(&sums[tid], (unsigned long long)(long long)sred[tid]);
    atomicAdd(&sums[256 + tid], (unsigned long long)(long long)sred[256 + tid]);
  }
}

// ---------------- finalize: BN params + binarize thresholds ----------------
// par layout (floats): [0:256) mean, [256:512) A=gamma*istd, [512:768) beta,
//                      [768:1024) thr, [1024:1280) sflip (as int bits)

__global__ void finalize_kernel(const unsigned long long* __restrict__ sums,
                                const float* __restrict__ gamma, const float* __restrict__ beta,
                                float* __restrict__ par) {
  const int c = threadIdx.x;
  double S = (double)(long long)sums[c];
  double Q = (double)(long long)sums[256 + c];
  double mean = S / 50176.0;
  double var = Q / 50176.0 - mean * mean;
  double istd = 1.0 / sqrt(var + 1e-5);
  double A = (double)gamma[c] * istd;
  float Af = (float)A;
  par[c] = (float)mean;
  par[256 + c] = Af;
  par[512 + c] = beta[c];
  float thr; int sf;
  if (Af > 0.f)      { thr = (float)(mean - (double)beta[c] / A); sf = 1; }
  else if (Af < 0.f) { thr = (float)(mean - (double)beta[c] / A); sf = -1; }
  else               { thr = -1e30f; sf = (beta[c] > 0.f) ? 1 : ((beta[c] < 0.f) ? -1 : 0); }
  par[768 + c] = thr;
  ((int*)par)[1024 + c] = sf;
}

// ---------------- final: BN2 + residual, NHWC -> NCHW ----------------

__global__ void final_kernel(const int16_t* __restrict__ raw2, const float* __restrict__ par,
                             const float* __restrict__ x, float* __restrict__ out) {
  __shared__ float t[256 * 57];
  const int tid = threadIdx.x;
  const int h = blockIdx.x, b = blockIdx.y;
  const int rowp = b * 3136 + h * 56;
  for (int i = 0; i < 7; ++i) {
    int f8 = i * 256 + tid;
    int px = f8 >> 5, c0 = (f8 & 31) << 3;
    float m[8], A[8], bb[8];
    *(float4*)&m[0]  = *(const float4*)&par[c0];
    *(float4*)&m[4]  = *(const float4*)&par[c0 + 4];
    *(float4*)&A[0]  = *(const float4*)&par[256 + c0];
    *(float4*)&A[4]  = *(const float4*)&par[256 + c0 + 4];
    *(float4*)&bb[0] = *(const float4*)&par[512 + c0];
    *(float4*)&bb[4] = *(const float4*)&par[512 + c0 + 4];
    v4i vv = *(const v4i*)(raw2 + (size_t)(rowp + px) * 256 + c0);
    #pragma unroll
    for (int j = 0; j < 8; ++j) {
      int wd = vv[j >> 1];
      int v = (j & 1) ? (wd >> 16) : (int)(short)wd;
      t[(c0 + j) * 57 + px] = ((float)v - m[j]) * A[j] + bb[j];
    }
  }
  __syncthreads();
  const float* xb = x + (size_t)b * 802816 + (size_t)h * 56;
  float* ob = out + (size_t)b * 802816 + (size_t)h * 56;
  for (int i = 0; i < 16; ++i) {
    int idx = i * 256 + tid;            // 256c x 16 slots (14 valid)
    int c = idx >> 4, wq = idx & 15;
    if (wq < 14) {
      int w0 = wq * 4;
      float4 xv = *(const float4*)(xb + (size_t)c * 3136 + w0);
      float4 o;
      o.x = t[c * 57 + w0 + 0] + xv.x;
      o.y = t[c * 57 + w0 + 1] + xv.y;
      o.z = t[c * 57 + w0 + 2] + xv.z;
      o.w = t[c * 57 + w0 + 3] + xv.w;
      *(float4*)(ob + (size_t)c * 3136 + w0) = o;
    }
  }
}

// ---------------- host launcher ----------------

extern "C" void kernel_launch(void* const* d_in, const int* in_sizes, int n_in,
                              void* d_out, int out_size, void* d_ws, size_t ws_size,
                              hipStream_t stream) {
  const float* x      = (const float*)d_in[0];
  const float* z1     = (const float*)d_in[1];
  const float* W0_1   = (const float*)d_in[2];
  const float* W2_1   = (const float*)d_in[3];
  const float* W3_1   = (const float*)d_in[4];
  const float* gamma1 = (const float*)d_in[5];
  const float* beta1  = (const float*)d_in[6];
  const float* z2     = (const float*)d_in[7];
  const float* W0_2   = (const float*)d_in[8];
  const float* W2_2   = (const float*)d_in[9];
  const float* W3_2   = (const float*)d_in[10];
  const float* gamma2 = (const float*)d_in[11];
  const float* beta2  = (const float*)d_in[12];
  float* out = (float*)d_out;

  char* ws = (char*)d_ws;
  size_t off = 0;
  auto alloc = [&](size_t sz) -> void* {
    void* p = ws + off;
    off += (sz + 255) & ~(size_t)255;
    return p;
  };
  int8_t* Sp1   = (int8_t*)alloc(13778944);          // 16*58*58*256
  int16_t* raw1 = (int16_t*)alloc(25690112);         // 50176*256*2
  int16_t* raw2 = (int16_t*)alloc(25690112);
  int8_t* Wb1   = (int8_t*)alloc(589824);
  int8_t* Wb2   = (int8_t*)alloc(589824);
  int* b1       = (int*)alloc(1024);
  int* b2       = (int*)alloc(1024);
  float* nrm    = (float*)alloc(8192);               // nrm1 | nrm2
  unsigned long long* sums = (unsigned long long*)alloc(8192); // sums1 | sums2
  float* par1   = (float*)alloc(5120);
  float* par2   = (float*)alloc(5120);
  if (ws_size < off) return;

  prep_kernel<<<40, 256, 0, stream>>>(W2_1, W2_2, nrm, sums, z1, W0_1, z2, W0_2, b1, b2);
  hyper_kernel<<<512, 256, 0, stream>>>(z1, W2_1, W3_1, z2, W2_2, W3_2, nrm, Wb1, Wb2);
  signx_kernel<<<dim3(58, 16), 256, 0, stream>>>(x, Sp1);
  conv_kernel<0><<<dim3(14, 16), 512, 0, stream>>>(Sp1, nullptr, nullptr, Wb1, b1, raw1, sums);
  finalize_kernel<<<1, 256, 0, stream>>>(sums, gamma1, beta1, par1);
  conv_kernel<1><<<dim3(14, 16), 512, 0, stream>>>(nullptr, raw1, par1, Wb2, b2, raw2, sums + 512);
  finalize_kernel<<<1, 256, 0, stream>>>(sums + 512, gamma2, beta2, par2);
  final_kernel<<<dim3(56, 16), 256, 0, stream>>>(raw2, par2, x, out);
}